// Round 15
// baseline (184.591 us; speedup 1.0000x reference)
//
#include <hip/hip_runtime.h>

// Problem: B=4, C=256, N=H*W=4096, GROUPS=16, qkv: 768x256, proj: 256x256.
// Pipeline (5 kernels): gnw -> gn_apply -> qkv GEMM (bf16 core, fp8 q/k/v epilogues, 64-key
// swizzled K/V^T tiles) -> flash attention (Bc=64; BOTH S and PV via MX-scaled
// mfma_scale_f32_32x32x64_f8f6f4 (scale=1.0); raw v_exp_f32 no-max softmax, KV-split=4,
// double-buffered global_load_lds) -> proj GEMM (fused combine + residual)

typedef unsigned short u16;
typedef unsigned char  u8;
typedef __attribute__((ext_vector_type(8)))  short short8;
typedef __attribute__((ext_vector_type(4)))  float f32x4;
typedef __attribute__((ext_vector_type(16))) float f32x16;
typedef __attribute__((ext_vector_type(8)))  int   i32x8;

// workspace byte offsets (~47 MB)
#define XN_OFF   0ull            // xn  [4][4096][256] bf16 (8,388,608 B)
#define OP_OFF   0ull            // opart [4][4][4096][256] bf16 overlays xn (33,554,432 B)
#define QW_OFF   33554432ull     // q fp8 [4][4096][256] (4,194,304 B)
#define KW_OFF   37748736ull     // k fp8 64-key swizzled tiles [4][64][16KB]
#define VW_OFF   41943040ull     // v^T fp8 64-key swizzled tiles [4][64][16KB]
#define LP_OFF   46137344ull     // lpart [4][4][4096] f32 (262,144 B)
#define WQB_OFF  46399488ull     // qkv_w bf16 (393,216 B)
#define WPB_OFF  46792704ull     // proj_w bf16 (131,072 B)
#define ST_OFF   46923776ull     // pstats [64][8][2] f32 (dedicated)

#define QSCALE 0.09016844f       // log2(e)/16 (applied to scores inside flash)
#define LDA 40                   // proj LDS stride (BK=32)
#define LDB 72                   // qkv LDS stride (BK=64)
#define SCL1 0x7F7F7F7F          // e8m0 scale = 1.0 in all four bytes

__device__ __forceinline__ u16 f2bf(float x){
  unsigned u = __float_as_uint(x);
  u += 0x7fffu + ((u >> 16) & 1u);          // RNE
  return (u16)(u >> 16);
}
__device__ __forceinline__ float bf2f(u16 h){
  return __uint_as_float(((unsigned)h) << 16);
}
__device__ __forceinline__ u8 f2fp8(float x){
  return (u8)(__builtin_amdgcn_cvt_pk_fp8_f32(x, x, 0, false) & 0xff);
}
// raw v_exp_f32: arg provably bounded, skip ocml range handling
__device__ __forceinline__ float fast_exp2(float x){
  float r;
  asm("v_exp_f32 %0, %1" : "=v"(r) : "v"(x));
  return r;
}

// ---------------- GN partial stats (512 blocks) + weight f32->bf16 (16 blocks) ----------------
__global__ __launch_bounds__(256) void gnw_k(const float* __restrict__ x, const float* __restrict__ wq,
                                             const float* __restrict__ wp, float* __restrict__ pstats,
                                             u16* __restrict__ wqb, u16* __restrict__ wpb){
  int t = threadIdx.x;
  if (blockIdx.y < 64){
    int bg = blockIdx.y, sl = blockIdx.x;
    const float* base = x + (size_t)bg*65536 + (size_t)sl*8192;
    float s = 0.f, ss = 0.f;
    for (int i = t; i < 2048; i += 256){
      float4 v = ((const float4*)base)[i];
      s  += (v.x + v.y) + (v.z + v.w);
      ss += (v.x*v.x + v.y*v.y) + (v.z*v.z + v.w*v.w);
    }
    for (int off = 32; off; off >>= 1){ s += __shfl_down(s, off, 64); ss += __shfl_down(ss, off, 64); }
    __shared__ float red[8];
    int wave = t >> 6, lane = t & 63;
    if (lane == 0){ red[wave] = s; red[4 + wave] = ss; }
    __syncthreads();
    if (t == 0){
      pstats[(bg*8 + sl)*2]     = red[0] + red[1] + red[2] + red[3];
      pstats[(bg*8 + sl)*2 + 1] = red[4] + red[5] + red[6] + red[7];
    }
  } else {
    int chunk = (blockIdx.y - 64)*8 + blockIdx.x;    // 0..15, 4096 float4 each
    for (int it = 0; it < 16; ++it){
      int i = chunk*4096 + it*256 + t;               // float4 index, 65536 total
      int elem = i*4;
      float4 v = (elem < 196608) ? ((const float4*)wq)[i] : ((const float4*)wp)[i - 49152];
      uint2 w;
      w.x = (unsigned)f2bf(v.x) | ((unsigned)f2bf(v.y) << 16);
      w.y = (unsigned)f2bf(v.z) | ((unsigned)f2bf(v.w) << 16);
      if (elem < 196608) *(uint2*)(wqb + elem)          = w;
      else               *(uint2*)(wpb + elem - 196608) = w;
    }
  }
}

// ---------------- GN finalize + apply + transpose: x[b][c][n] f32 -> xn[b][n][c] bf16 ----------------
__global__ __launch_bounds__(256) void gn_apply_k(const float* __restrict__ x, const float* __restrict__ gw,
                                                  const float* __restrict__ gb, const float* __restrict__ pstats,
                                                  u16* __restrict__ xn){
  int b = blockIdx.z, c0 = blockIdx.y*64, n0 = blockIdx.x*64;
  __shared__ float tile[64*65];
  __shared__ float gmu[4], grs[4];
  int t = threadIdx.x;
  if (t < 4){
    int gidx = (b*16 + (c0 >> 4) + t)*8;
    float S = 0.f, SS = 0.f;
    for (int k2 = 0; k2 < 8; ++k2){ S += pstats[(gidx + k2)*2]; SS += pstats[(gidx + k2)*2 + 1]; }
    float mu = S*(1.f/65536.f);
    gmu[t] = mu;
    grs[t] = rsqrtf(SS*(1.f/65536.f) - mu*mu + 1e-5f);
  }
  __syncthreads();
  for (int i = 0; i < 4; ++i){
    int idx = i*256 + t;                 // 0..1023 -> 64 c-rows x 16 float4
    int cl = idx >> 4, q4 = idx & 15;
    int c = c0 + cl;
    float4 v = *(const float4*)(x + ((size_t)b*256 + c)*4096 + n0 + q4*4);
    float mu = gmu[cl>>4], rs = grs[cl>>4];
    float w = gw[c], bi = gb[c];
    tile[cl*65 + q4*4 + 0] = (v.x - mu)*rs*w + bi;
    tile[cl*65 + q4*4 + 1] = (v.y - mu)*rs*w + bi;
    tile[cl*65 + q4*4 + 2] = (v.z - mu)*rs*w + bi;
    tile[cl*65 + q4*4 + 3] = (v.w - mu)*rs*w + bi;
  }
  __syncthreads();
  for (int i = 0; i < 4; ++i){
    int idx = i*256 + t;                 // 0..1023 -> 64 n-rows x 16 channel-quads
    int nl = idx >> 4, cq = idx & 15;
    int cl = cq*4;
    uint2 w;
    w.x = (unsigned)f2bf(tile[(cl+0)*65 + nl]) | ((unsigned)f2bf(tile[(cl+1)*65 + nl]) << 16);
    w.y = (unsigned)f2bf(tile[(cl+2)*65 + nl]) | ((unsigned)f2bf(tile[(cl+3)*65 + nl]) << 16);
    *(uint2*)(xn + ((size_t)b*4096 + n0 + nl)*256 + c0 + cl) = w;
  }
}

// ---------------- qkv GEMM: BK=64 bf16 core; fp8 epilogues; 64-key K/V^T tiles ----------------
__global__ __launch_bounds__(256) void qkv_gemm_k(const u16* __restrict__ xn, const u16* __restrict__ wq,
        const float* __restrict__ qb, u8* __restrict__ q, u8* __restrict__ k, u8* __restrict__ v){
  int bx = blockIdx.x;           // 0-1:q, 2-3:k, 4-5:v
  int m0 = blockIdx.y*128;
  int b  = blockIdx.z;
  __shared__ u16 smem[2*128*LDB];   // 36 KB; v-transpose epilogue reuses 32 KB
  u16* As = smem;
  u16* Bs = smem + 128*LDB;
  int t = threadIdx.x, lane = t & 63, wave = t >> 6;
  int wm = wave >> 1, wn = wave & 1;
  int c15 = lane & 15, g = lane >> 4;
  f32x4 acc[4][4];
  for (int mt = 0; mt < 4; ++mt) for (int nt = 0; nt < 4; ++nt) acc[mt][nt] = (f32x4){0.f,0.f,0.f,0.f};
  const u16* abase = xn + ((size_t)b*4096 + m0)*256;
  const u16* bbase = wq + (size_t)bx*128*256;
  for (int kk = 0; kk < 4; ++kk){
    int k0 = kk*64;
    for (int it = 0; it < 4; ++it){
      int idx = it*256 + t;
      int row = idx >> 3, ch = idx & 7;
      uint4 va = *(const uint4*)(abase + (size_t)row*256 + k0 + ch*8);
      *(uint4*)(As + row*LDB + ch*8) = va;
      uint4 vb = *(const uint4*)(bbase + (size_t)row*256 + k0 + ch*8);
      *(uint4*)(Bs + row*LDB + ch*8) = vb;
    }
    __syncthreads();
    for (int half = 0; half < 2; ++half){
      short8 af[4], bfr[4];
      for (int mt = 0; mt < 4; ++mt) af[mt]  = *(const short8*)(As + (wm*64 + mt*16 + c15)*LDB + half*32 + g*8);
      for (int nt = 0; nt < 4; ++nt) bfr[nt] = *(const short8*)(Bs + (wn*64 + nt*16 + c15)*LDB + half*32 + g*8);
      for (int mt = 0; mt < 4; ++mt)
        for (int nt = 0; nt < 4; ++nt)
          acc[mt][nt] = __builtin_amdgcn_mfma_f32_16x16x32_bf16(af[mt], bfr[nt], acc[mt][nt], 0, 0, 0);
    }
    __syncthreads();
  }
  if (bx < 2){
    // q: fp8 linear [b][n][256] (unscaled; QSCALE applied in flash)
    for (int nt = 0; nt < 4; ++nt){
      int col = bx*128 + wn*64 + nt*16 + c15;
      float bias = qb[col];
      for (int mt = 0; mt < 4; ++mt){
        int m = m0 + wm*64 + mt*16 + g*4;
        for (int r = 0; r < 4; ++r)
          q[((size_t)b*4096 + m + r)*256 + col] = f2fp8(acc[mt][nt][r] + bias);
      }
    }
  } else if (bx < 4){
    // k: fp8 64-key swizzled tiles (chunk swizzle n&15, r11/r14-verified)
    for (int nt = 0; nt < 4; ++nt){
      int col = bx*128 + wn*64 + nt*16 + c15;
      int c = col - 256;
      float bias = qb[col];
      for (int mt = 0; mt < 4; ++mt){
        int m = m0 + wm*64 + mt*16 + g*4;
        for (int r = 0; r < 4; ++r){
          int n = m + r;
          size_t addr = ((size_t)b*64 + (n >> 6))*16384 +
                        (size_t)((n & 63)*256 + (((c >> 3) ^ (n & 15)) << 3) + (c & 7));
          k[addr] = f2fp8(acc[mt][nt][r] + bias);
        }
      }
    }
  } else {
    // v: bf16 LDS transpose, then fp8 64-key swizzled v^T tiles (r11/r14-verified layout)
    __syncthreads();
    char* Tb = (char*)smem;
    for (int nt = 0; nt < 4; ++nt){
      int o_l = wn*64 + nt*16 + c15;
      float bias = qb[bx*128 + o_l];
      for (int mt = 0; mt < 4; ++mt){
        int mb = wm*64 + mt*16 + g*4;
        unsigned p0 = (unsigned)f2bf(acc[mt][nt][0] + bias) | ((unsigned)f2bf(acc[mt][nt][1] + bias) << 16);
        unsigned p1 = (unsigned)f2bf(acc[mt][nt][2] + bias) | ((unsigned)f2bf(acc[mt][nt][3] + bias) << 16);
        int base = o_l*256 + (((mb >> 3) ^ (o_l & 7)) << 4) + ((mb & 7) << 1);
        *(unsigned*)(Tb + base)     = p0;
        *(unsigned*)(Tb + base + 4) = p1;
      }
    }
    __syncthreads();
    for (int it = 0; it < 8; ++it){
      int idx = it*256 + t;
      int ro = idx >> 4, ch = idx & 15;
      uint4 val = *(const uint4*)(Tb + ro*256 + ((ch ^ (ro & 7)) << 4));
      int c = bx*128 - 512 + ro;          // absolute channel
      int n = m0 + ch*8;                  // aligned 8-key chunk
      float f0 = bf2f((u16)(val.x & 0xffff)), f1 = bf2f((u16)(val.x >> 16));
      float f2 = bf2f((u16)(val.y & 0xffff)), f3 = bf2f((u16)(val.y >> 16));
      float f4 = bf2f((u16)(val.z & 0xffff)), f5 = bf2f((u16)(val.z >> 16));
      float f6 = bf2f((u16)(val.w & 0xffff)), f7 = bf2f((u16)(val.w >> 16));
      int w0 = __builtin_amdgcn_cvt_pk_fp8_f32(f0, f1, 0, false);
      w0     = __builtin_amdgcn_cvt_pk_fp8_f32(f2, f3, w0, true);
      int w1 = __builtin_amdgcn_cvt_pk_fp8_f32(f4, f5, 0, false);
      w1     = __builtin_amdgcn_cvt_pk_fp8_f32(f6, f7, w1, true);
      size_t addr = ((size_t)b*64 + (n >> 6))*16384 +
                    (size_t)(c*64 + ((((n >> 3) & 7) ^ ((c >> 1) & 7)) << 3));
      uint2 wv; wv.x = (unsigned)w0; wv.y = (unsigned)w1;
      *(uint2*)(v + addr) = wv;
    }
  }
}

// ---------------- flash attention: Bc=64, scaled-S AND scaled-PV (K=64), double-buffered DMA ----------------
// waitcnt imms: vmcnt(8)=0x0F78, vmcnt(0)=0x0F70, lgkmcnt(0)=0xC07F
__global__ __launch_bounds__(256, 2) void flash_k(const u8* __restrict__ q, const u8* __restrict__ kt,
                                                  const u8* __restrict__ vt, u16* __restrict__ opart,
                                                  float* __restrict__ lpart){
  int n0 = blockIdx.x*128;
  int jh = blockIdx.y;
  int b  = blockIdx.z;
  __shared__ char buf[2][32768];   // 2 x 32KB: [K tile 16KB][V^T tile 16KB]
  int t = threadIdx.x, lane = t & 63, wave = t >> 6;
  int il = lane & 31;
  int h  = lane >> 5;

  // Q B-frags for scaled MFMA: lane holds Q[i=il][ch = si*64 + h*32 + e], e=0..31
  i32x8 qf8[4];
  const u8* qrow = q + ((size_t)b*4096 + n0 + wave*32 + il)*256;
  #pragma unroll
  for (int si = 0; si < 4; ++si){
    uint4 a0 = *(const uint4*)(qrow + si*64 + h*32);
    uint4 a1 = *(const uint4*)(qrow + si*64 + h*32 + 16);
    qf8[si] = (i32x8){(int)a0.x,(int)a0.y,(int)a0.z,(int)a0.w,(int)a1.x,(int)a1.y,(int)a1.z,(int)a1.w};
  }

  f32x16 oacc[8];
  #pragma unroll
  for (int ct = 0; ct < 8; ++ct){
    #pragma unroll
    for (int r = 0; r < 16; ++r) oacc[ct][r] = 0.f;
  }
  float lsum = 0.f;

  size_t tb0 = ((size_t)b*64 + jh*16) * 16384;
  const char* gK = (const char*)kt + tb0;
  const char* gV = (const char*)vt + tb0;
  const char* gsrc = (wave < 2) ? (gK + wave*8192) : (gV + (wave - 2)*8192);
  unsigned lds_off = wave*8192;    // waves 0-1 -> K half [0,16K), waves 2-3 -> V half [16K,32K)

  // prime tiles 0 and 1 (8 x 1KB chunks per wave per tile)
  {
    const char* g0 = gsrc + (size_t)lane*16;
    #pragma unroll
    for (int i = 0; i < 8; ++i)
      __builtin_amdgcn_global_load_lds((const __attribute__((address_space(1))) void*)(g0 + i*1024),
          (__attribute__((address_space(3))) void*)((char*)buf[0] + lds_off + i*1024), 16, 0, 0);
    const char* g1 = gsrc + 16384 + (size_t)lane*16;
    #pragma unroll
    for (int i = 0; i < 8; ++i)
      __builtin_amdgcn_global_load_lds((const __attribute__((address_space(1))) void*)(g1 + i*1024),
          (__attribute__((address_space(3))) void*)((char*)buf[1] + lds_off + i*1024), 16, 0, 0);
  }

  for (int jt = 0; jt < 16; ++jt){
    int p = jt & 1;
    asm volatile("" ::: "memory");
    if (jt < 15) __builtin_amdgcn_s_waitcnt(0x0F78);   // vmcnt(8): tile jt landed, jt+1 in flight
    else         __builtin_amdgcn_s_waitcnt(0x0F70);   // vmcnt(0)
    __builtin_amdgcn_s_barrier();
    asm volatile("" ::: "memory");

    const char* klds = buf[p];
    const char* vlds = buf[p] + 16384;

    // K=64 A-frag of P under construction: lane (il,h) will hold P[query il][keys h*32..h*32+31]
    unsigned paf[8];
    #pragma unroll 1
    for (int jg = 0; jg < 2; ++jg){
      // S^T (32 keys x 32 queries) for key subtile jg: 4 MX-scaled K=64 MFMAs (scale = 1.0)
      f32x16 s0;
      #pragma unroll
      for (int r = 0; r < 16; ++r) s0[r] = 0.f;
      const char* krow = klds + (jg*32 + il)*256;
      #pragma unroll
      for (int si = 0; si < 4; ++si){
        uint2 c0 = *(const uint2*)(krow + (((si*8 + h*4 + 0) ^ (il & 15)) << 3));
        uint2 c1 = *(const uint2*)(krow + (((si*8 + h*4 + 1) ^ (il & 15)) << 3));
        uint2 c2 = *(const uint2*)(krow + (((si*8 + h*4 + 2) ^ (il & 15)) << 3));
        uint2 c3 = *(const uint2*)(krow + (((si*8 + h*4 + 3) ^ (il & 15)) << 3));
        i32x8 kf8 = (i32x8){(int)c0.x,(int)c0.y,(int)c1.x,(int)c1.y,(int)c2.x,(int)c2.y,(int)c3.x,(int)c3.y};
        s0 = __builtin_amdgcn_mfma_scale_f32_32x32x64_f8f6f4(kf8, qf8[si], s0,
                                                             0, 0, 0, SCL1, 0, SCL1);
      }
      // no-max softmax numerator; D: lane holds S^T[j=(r&3)+8(r>>2)+4h][i=il]
      float pv[16];
      #pragma unroll
      for (int r = 0; r < 16; ++r){
        float e = fast_exp2(s0[r] * QSCALE);
        pv[r] = e;
        lsum += e;
      }
      // pack own 16 p-values (j = base + 0..3, base = 8*g2 + 4h) and exchange with lane^32;
      // the jg==h half commits its K=64 frag slice: fr[2q]=h?rr:own, fr[2q+1]=h?own:rr
      unsigned own[4], rr[4];
      #pragma unroll
      for (int g2 = 0; g2 < 4; ++g2){
        int q0 = __builtin_amdgcn_cvt_pk_fp8_f32(pv[4*g2+0], pv[4*g2+1], 0, false);
        q0     = __builtin_amdgcn_cvt_pk_fp8_f32(pv[4*g2+2], pv[4*g2+3], q0, true);
        own[g2] = (unsigned)q0;
      }
      #pragma unroll
      for (int g2 = 0; g2 < 4; ++g2)
        rr[g2] = (unsigned)__shfl_xor((int)own[g2], 32, 64);
      if (jg == h){
        #pragma unroll
        for (int g2 = 0; g2 < 4; ++g2){
          paf[2*g2]     = h ? rr[g2]  : own[g2];
          paf[2*g2 + 1] = h ? own[g2] : rr[g2];
        }
      }
    }
    // O += P*V : 8 MX-scaled K=64 MFMAs (keys 0..63 of this jt)
    i32x8 pa8 = (i32x8){(int)paf[0],(int)paf[1],(int)paf[2],(int)paf[3],
                        (int)paf[4],(int)paf[5],(int)paf[6],(int)paf[7]};
    #pragma unroll
    for (int ct = 0; ct < 8; ++ct){
      int c = ct*32 + il;
      const char* vrow = vlds + c*64;
      uint2 b0 = *(const uint2*)(vrow + (((4*h + 0) ^ ((c >> 1) & 7)) << 3));
      uint2 b1 = *(const uint2*)(vrow + (((4*h + 1) ^ ((c >> 1) & 7)) << 3));
      uint2 b2 = *(const uint2*)(vrow + (((4*h + 2) ^ ((c >> 1) & 7)) << 3));
      uint2 b3 = *(const uint2*)(vrow + (((4*h + 3) ^ ((c >> 1) & 7)) << 3));
      i32x8 vf8 = (i32x8){(int)b0.x,(int)b0.y,(int)b1.x,(int)b1.y,
                          (int)b2.x,(int)b2.y,(int)b3.x,(int)b3.y};
      oacc[ct] = __builtin_amdgcn_mfma_scale_f32_32x32x64_f8f6f4(pa8, vf8, oacc[ct],
                                                                 0, 0, 0, SCL1, 0, SCL1);
    }

    asm volatile("" ::: "memory");
    __builtin_amdgcn_s_waitcnt(0xC07F);     // lgkmcnt(0): my LDS reads retired
    __builtin_amdgcn_s_barrier();           // all waves done reading buf[p]
    asm volatile("" ::: "memory");
    if (jt + 2 < 16){
      const char* gn2 = gsrc + (size_t)(jt + 2)*16384 + (size_t)lane*16;
      #pragma unroll
      for (int i = 0; i < 8; ++i)
        __builtin_amdgcn_global_load_lds((const __attribute__((address_space(1))) void*)(gn2 + i*1024),
            (__attribute__((address_space(3))) void*)((char*)buf[p] + lds_off + i*1024), 16, 0, 0);
    }
  }

  // epilogue
  float tot = lsum + __shfl_xor(lsum, 32, 64);
  if (h == 0) lpart[(size_t)(jh*4 + b)*4096 + n0 + wave*32 + il] = tot;
  u16* obase = opart + ((size_t)(jh*4 + b)*4096 + n0 + wave*32)*256;
  #pragma unroll
  for (int ct = 0; ct < 8; ++ct){
    #pragma unroll
    for (int r = 0; r < 16; ++r){
      int i = (r & 3) + 8*(r >> 2) + 4*h;
      obase[(size_t)i*256 + ct*32 + il] = f2bf(oacc[ct][r]);
    }
  }
}

// ---------------- proj GEMM, n-tile 32 (512 blocks), fused combine + bias + residual ----------------
__global__ __launch_bounds__(256) void proj_gemm_k(const u16* __restrict__ opart, const float* __restrict__ lpart,
        const u16* __restrict__ wp, const float* __restrict__ pb, const float* __restrict__ x,
        float* __restrict__ out){
  int n0 = blockIdx.x*32;
  int b  = blockIdx.y;
  __shared__ u16 As[256*LDA];    // proj_w chunk 256 x 32
  __shared__ u16 Bs[32*LDA];     // combined ao chunk 32 x 32
  __shared__ float linv[32];
  int t = threadIdx.x, lane = t & 63, wave = t >> 6;
  int c15 = lane & 15, g = lane >> 4;
  if (t < 32){
    size_t row = (size_t)b*4096 + n0 + t;
    linv[t] = 1.0f / (lpart[row] + lpart[16384 + row] + lpart[32768 + row] + lpart[49152 + row]);
  }
  f32x4 acc[4][2];
  for (int mt = 0; mt < 4; ++mt) for (int nt = 0; nt < 2; ++nt) acc[mt][nt] = (f32x4){0.f,0.f,0.f,0.f};
  __syncthreads();
  for (int kk = 0; kk < 8; ++kk){
    int k0 = kk*32;
    for (int it = 0; it < 4; ++it){
      int idx = it*256 + t;
      int row = idx >> 2, ch = idx & 3;
      *(uint4*)(As + row*LDA + ch*8) = *(const uint4*)(wp + (size_t)row*256 + k0 + ch*8);
    }
    if (t < 128){
      int row = t >> 2, ch = t & 3;     // 32 rows x 4 chunks
      const u16* bptr = opart + ((size_t)b*4096 + n0 + row)*256 + k0 + ch*8;
      uint4 o0 = *(const uint4*)(bptr);
      uint4 o1 = *(const uint4*)(bptr + 4194304ull);
      uint4 o2 = *(const uint4*)(bptr + 8388608ull);
      uint4 o3 = *(const uint4*)(bptr + 12582912ull);
      float inv = linv[row];
      const unsigned* u0 = (const unsigned*)&o0;
      const unsigned* u1 = (const unsigned*)&o1;
      const unsigned* u2 = (const unsigned*)&o2;
      const unsigned* u3 = (const unsigned*)&o3;
      uint4 w;
      unsigned* wpk = (unsigned*)&w;
      for (int i = 0; i < 4; ++i){
        float lo = (bf2f((u16)(u0[i] & 0xffff)) + bf2f((u16)(u1[i] & 0xffff)) +
                    bf2f((u16)(u2[i] & 0xffff)) + bf2f((u16)(u3[i] & 0xffff))) * inv;
        float hi = (bf2f((u16)(u0[i] >> 16))    + bf2f((u16)(u1[i] >> 16)) +
                    bf2f((u16)(u2[i] >> 16))    + bf2f((u16)(u3[i] >> 16)))    * inv;
        wpk[i] = (unsigned)f2bf(lo) | ((unsigned)f2bf(hi) << 16);
      }
      *(uint4*)(Bs + row*LDA + ch*8) = w;
    }
    __syncthreads();
    short8 af[4], bfr[2];
    for (int mt = 0; mt < 4; ++mt) af[mt]  = *(const short8*)(As + (wave*64 + mt*16 + c15)*LDA + g*8);
    for (int nt = 0; nt < 2; ++nt) bfr[nt] = *(const short8*)(Bs + (nt*16 + c15)*LDA + g*8);
    for (int mt = 0; mt < 4; ++mt)
      for (int nt = 0; nt < 2; ++nt)
        acc[mt][nt] = __builtin_amdgcn_mfma_f32_16x16x32_bf16(af[mt], bfr[nt], acc[mt][nt], 0, 0, 0);
    __syncthreads();
  }
  for (int mt = 0; mt < 4; ++mt){
    for (int r = 0; r < 4; ++r){
      int o = wave*64 + mt*16 + g*4 + r;
      float bias = pb[o];
      for (int nt = 0; nt < 2; ++nt){
        int n = n0 + nt*16 + c15;
        size_t off = ((size_t)b*256 + o)*4096 + n;
        out[off] = x[off] + bias + acc[mt][nt][r];
      }
    }
  }
}

extern "C" void kernel_launch(void* const* d_in, const int* in_sizes, int n_in,
                              void* d_out, int out_size, void* d_ws, size_t ws_size,
                              hipStream_t stream){
  (void)in_sizes; (void)n_in; (void)out_size; (void)ws_size;
  const float* x     = (const float*)d_in[0];
  const float* gw    = (const float*)d_in[1];
  const float* gb    = (const float*)d_in[2];
  const float* qkvw  = (const float*)d_in[3];
  const float* qkvb  = (const float*)d_in[4];
  const float* projw = (const float*)d_in[5];
  const float* projb = (const float*)d_in[6];
  float* out = (float*)d_out;
  char* ws = (char*)d_ws;

  u16*   xn    = (u16*)(ws + XN_OFF);     // overlays opart (dead until flash writes it)
  u16*   op    = (u16*)(ws + OP_OFF);
  u8*    qws   = (u8*)(ws + QW_OFF);
  u8*    kws   = (u8*)(ws + KW_OFF);
  u8*    vws   = (u8*)(ws + VW_OFF);
  float* lp    = (float*)(ws + LP_OFF);
  u16*   wqb   = (u16*)(ws + WQB_OFF);
  u16*   wpb   = (u16*)(ws + WPB_OFF);
  float* pstat = (float*)(ws + ST_OFF);

  gnw_k<<<dim3(8, 66), 256, 0, stream>>>(x, qkvw, projw, pstat, wqb, wpb);
  gn_apply_k<<<dim3(64, 4, 4), 256, 0, stream>>>(x, gw, gb, pstat, xn);
  qkv_gemm_k<<<dim3(6, 32, 4), 256, 0, stream>>>(xn, wqb, qkvb, qws, kws, vws);
  flash_k<<<dim3(32, 4, 4), 256, 0, stream>>>(qws, kws, vws, op, lp);
  proj_gemm_k<<<dim3(128, 4), 256, 0, stream>>>(op, lp, wpb, projb, x, out);
}

// Round 16
// 163.828 us; speedup vs baseline: 1.1267x; 1.1267x over previous
//
#include <hip/hip_runtime.h>

// Problem: B=4, C=256, N=H*W=4096, GROUPS=16, qkv: 768x256, proj: 256x256.
// Pipeline (5 kernels, r13-exact): gnw -> gn_apply -> qkv GEMM (bf16 core, fp8 q/k/v epilogues) ->
// flash attention (S via MX-scaled mfma_scale_f32_32x32x64_f8f6f4 (scale=1.0), PV via
// 32x32x16_fp8, Bc=32, raw v_exp_f32 no-max softmax, KV-split=4, double-buffered
// global_load_lds) -> proj GEMM (fused KV-split combine + bias + residual)

typedef unsigned short u16;
typedef unsigned char  u8;
typedef __attribute__((ext_vector_type(8)))  short short8;
typedef __attribute__((ext_vector_type(4)))  float f32x4;
typedef __attribute__((ext_vector_type(16))) float f32x16;
typedef __attribute__((ext_vector_type(8)))  int   i32x8;

// workspace byte offsets (~47 MB)
#define XN_OFF   0ull            // xn  [4][4096][256] bf16 (8,388,608 B)
#define OP_OFF   0ull            // opart [4][4][4096][256] bf16 overlays xn (33,554,432 B)
#define QW_OFF   33554432ull     // q fp8 [4][4096][256] (4,194,304 B)
#define KW_OFF   37748736ull     // k fp8 tiled-swizzled [4][128][8KB]
#define VW_OFF   41943040ull     // v^T fp8 tiled-swizzled [4][128][8KB]
#define LP_OFF   46137344ull     // lpart [4][4][4096] f32 (262,144 B)
#define WQB_OFF  46399488ull     // qkv_w bf16 (393,216 B)
#define WPB_OFF  46792704ull     // proj_w bf16 (131,072 B)
#define ST_OFF   46923776ull     // pstats [64][8][2] f32 (dedicated)

#define QSCALE 0.09016844f       // log2(e)/16 (applied to scores inside flash)
#define LDA 40                   // proj LDS stride (BK=32)
#define LDB 72                   // qkv LDS stride (BK=64)
#define SCL1 0x7F7F7F7F          // e8m0 scale = 1.0 in all four bytes

__device__ __forceinline__ u16 f2bf(float x){
  unsigned u = __float_as_uint(x);
  u += 0x7fffu + ((u >> 16) & 1u);          // RNE
  return (u16)(u >> 16);
}
__device__ __forceinline__ float bf2f(u16 h){
  return __uint_as_float(((unsigned)h) << 16);
}
__device__ __forceinline__ u8 f2fp8(float x){
  return (u8)(__builtin_amdgcn_cvt_pk_fp8_f32(x, x, 0, false) & 0xff);
}
// raw v_exp_f32: arg provably bounded, skip ocml range handling
__device__ __forceinline__ float fast_exp2(float x){
  float r;
  asm("v_exp_f32 %0, %1" : "=v"(r) : "v"(x));
  return r;
}

// ---------------- GN partial stats (512 blocks) + weight f32->bf16 (16 blocks) ----------------
__global__ __launch_bounds__(256) void gnw_k(const float* __restrict__ x, const float* __restrict__ wq,
                                             const float* __restrict__ wp, float* __restrict__ pstats,
                                             u16* __restrict__ wqb, u16* __restrict__ wpb){
  int t = threadIdx.x;
  if (blockIdx.y < 64){
    int bg = blockIdx.y, sl = blockIdx.x;
    const float* base = x + (size_t)bg*65536 + (size_t)sl*8192;
    float s = 0.f, ss = 0.f;
    for (int i = t; i < 2048; i += 256){
      float4 v = ((const float4*)base)[i];
      s  += (v.x + v.y) + (v.z + v.w);
      ss += (v.x*v.x + v.y*v.y) + (v.z*v.z + v.w*v.w);
    }
    for (int off = 32; off; off >>= 1){ s += __shfl_down(s, off, 64); ss += __shfl_down(ss, off, 64); }
    __shared__ float red[8];
    int wave = t >> 6, lane = t & 63;
    if (lane == 0){ red[wave] = s; red[4 + wave] = ss; }
    __syncthreads();
    if (t == 0){
      pstats[(bg*8 + sl)*2]     = red[0] + red[1] + red[2] + red[3];
      pstats[(bg*8 + sl)*2 + 1] = red[4] + red[5] + red[6] + red[7];
    }
  } else {
    int chunk = (blockIdx.y - 64)*8 + blockIdx.x;    // 0..15, 4096 float4 each
    for (int it = 0; it < 16; ++it){
      int i = chunk*4096 + it*256 + t;               // float4 index, 65536 total
      int elem = i*4;
      float4 v = (elem < 196608) ? ((const float4*)wq)[i] : ((const float4*)wp)[i - 49152];
      uint2 w;
      w.x = (unsigned)f2bf(v.x) | ((unsigned)f2bf(v.y) << 16);
      w.y = (unsigned)f2bf(v.z) | ((unsigned)f2bf(v.w) << 16);
      if (elem < 196608) *(uint2*)(wqb + elem)          = w;
      else               *(uint2*)(wpb + elem - 196608) = w;
    }
  }
}

// ---------------- GN finalize + apply + transpose: x[b][c][n] f32 -> xn[b][n][c] bf16 ----------------
__global__ __launch_bounds__(256) void gn_apply_k(const float* __restrict__ x, const float* __restrict__ gw,
                                                  const float* __restrict__ gb, const float* __restrict__ pstats,
                                                  u16* __restrict__ xn){
  int b = blockIdx.z, c0 = blockIdx.y*64, n0 = blockIdx.x*64;
  __shared__ float tile[64*65];
  __shared__ float gmu[4], grs[4];
  int t = threadIdx.x;
  if (t < 4){
    int gidx = (b*16 + (c0 >> 4) + t)*8;
    float S = 0.f, SS = 0.f;
    for (int k2 = 0; k2 < 8; ++k2){ S += pstats[(gidx + k2)*2]; SS += pstats[(gidx + k2)*2 + 1]; }
    float mu = S*(1.f/65536.f);
    gmu[t] = mu;
    grs[t] = rsqrtf(SS*(1.f/65536.f) - mu*mu + 1e-5f);
  }
  __syncthreads();
  for (int i = 0; i < 4; ++i){
    int idx = i*256 + t;                 // 0..1023 -> 64 c-rows x 16 float4
    int cl = idx >> 4, q4 = idx & 15;
    int c = c0 + cl;
    float4 v = *(const float4*)(x + ((size_t)b*256 + c)*4096 + n0 + q4*4);
    float mu = gmu[cl>>4], rs = grs[cl>>4];
    float w = gw[c], bi = gb[c];
    tile[cl*65 + q4*4 + 0] = (v.x - mu)*rs*w + bi;
    tile[cl*65 + q4*4 + 1] = (v.y - mu)*rs*w + bi;
    tile[cl*65 + q4*4 + 2] = (v.z - mu)*rs*w + bi;
    tile[cl*65 + q4*4 + 3] = (v.w - mu)*rs*w + bi;
  }
  __syncthreads();
  for (int i = 0; i < 4; ++i){
    int idx = i*256 + t;                 // 0..1023 -> 64 n-rows x 16 channel-quads
    int nl = idx >> 4, cq = idx & 15;
    int cl = cq*4;
    uint2 w;
    w.x = (unsigned)f2bf(tile[(cl+0)*65 + nl]) | ((unsigned)f2bf(tile[(cl+1)*65 + nl]) << 16);
    w.y = (unsigned)f2bf(tile[(cl+2)*65 + nl]) | ((unsigned)f2bf(tile[(cl+3)*65 + nl]) << 16);
    *(uint2*)(xn + ((size_t)b*4096 + n0 + nl)*256 + c0 + cl) = w;
  }
}

// ---------------- qkv GEMM: BK=64 bf16 core; fp8 epilogues (r9-exact) ----------------
__global__ __launch_bounds__(256) void qkv_gemm_k(const u16* __restrict__ xn, const u16* __restrict__ wq,
        const float* __restrict__ qb, u8* __restrict__ q, u8* __restrict__ k, u8* __restrict__ v){
  int bx = blockIdx.x;           // 0-1:q, 2-3:k, 4-5:v
  int m0 = blockIdx.y*128;
  int b  = blockIdx.z;
  __shared__ u16 smem[2*128*LDB];   // 36 KB; v-transpose epilogue reuses 32 KB
  u16* As = smem;
  u16* Bs = smem + 128*LDB;
  int t = threadIdx.x, lane = t & 63, wave = t >> 6;
  int wm = wave >> 1, wn = wave & 1;
  int c15 = lane & 15, g = lane >> 4;
  f32x4 acc[4][4];
  for (int mt = 0; mt < 4; ++mt) for (int nt = 0; nt < 4; ++nt) acc[mt][nt] = (f32x4){0.f,0.f,0.f,0.f};
  const u16* abase = xn + ((size_t)b*4096 + m0)*256;
  const u16* bbase = wq + (size_t)bx*128*256;
  for (int kk = 0; kk < 4; ++kk){
    int k0 = kk*64;
    for (int it = 0; it < 4; ++it){
      int idx = it*256 + t;
      int row = idx >> 3, ch = idx & 7;
      uint4 va = *(const uint4*)(abase + (size_t)row*256 + k0 + ch*8);
      *(uint4*)(As + row*LDB + ch*8) = va;
      uint4 vb = *(const uint4*)(bbase + (size_t)row*256 + k0 + ch*8);
      *(uint4*)(Bs + row*LDB + ch*8) = vb;
    }
    __syncthreads();
    for (int half = 0; half < 2; ++half){
      short8 af[4], bfr[4];
      for (int mt = 0; mt < 4; ++mt) af[mt]  = *(const short8*)(As + (wm*64 + mt*16 + c15)*LDB + half*32 + g*8);
      for (int nt = 0; nt < 4; ++nt) bfr[nt] = *(const short8*)(Bs + (wn*64 + nt*16 + c15)*LDB + half*32 + g*8);
      for (int mt = 0; mt < 4; ++mt)
        for (int nt = 0; nt < 4; ++nt)
          acc[mt][nt] = __builtin_amdgcn_mfma_f32_16x16x32_bf16(af[mt], bfr[nt], acc[mt][nt], 0, 0, 0);
    }
    __syncthreads();
  }
  if (bx < 2){
    // q: fp8 linear [b][n][256] (unscaled; QSCALE applied in flash)
    for (int nt = 0; nt < 4; ++nt){
      int col = bx*128 + wn*64 + nt*16 + c15;
      float bias = qb[col];
      for (int mt = 0; mt < 4; ++mt){
        int m = m0 + wm*64 + mt*16 + g*4;
        for (int r = 0; r < 4; ++r)
          q[((size_t)b*4096 + m + r)*256 + col] = f2fp8(acc[mt][nt][r] + bias);
      }
    }
  } else if (bx < 4){
    // k: fp8 swizzled 32-row tiles (matches flash kf b64 reads)
    for (int nt = 0; nt < 4; ++nt){
      int col = bx*128 + wn*64 + nt*16 + c15;
      int c = col - 256;
      float bias = qb[col];
      for (int mt = 0; mt < 4; ++mt){
        int m = m0 + wm*64 + mt*16 + g*4;
        for (int r = 0; r < 4; ++r){
          int n = m + r;
          size_t addr = ((size_t)b*128 + (n >> 5))*8192 +
                        (size_t)((n & 31)*256 + (((c >> 3) ^ (n & 15)) << 3) + (c & 7));
          k[addr] = f2fp8(acc[mt][nt][r] + bias);
        }
      }
    }
  } else {
    // v: bf16 LDS transpose, then fp8 swizzled v^T tiles (matches flash vf b64 reads)
    __syncthreads();
    char* Tb = (char*)smem;
    for (int nt = 0; nt < 4; ++nt){
      int o_l = wn*64 + nt*16 + c15;
      float bias = qb[bx*128 + o_l];
      for (int mt = 0; mt < 4; ++mt){
        int mb = wm*64 + mt*16 + g*4;
        unsigned p0 = (unsigned)f2bf(acc[mt][nt][0] + bias) | ((unsigned)f2bf(acc[mt][nt][1] + bias) << 16);
        unsigned p1 = (unsigned)f2bf(acc[mt][nt][2] + bias) | ((unsigned)f2bf(acc[mt][nt][3] + bias) << 16);
        int base = o_l*256 + (((mb >> 3) ^ (o_l & 7)) << 4) + ((mb & 7) << 1);
        *(unsigned*)(Tb + base)     = p0;
        *(unsigned*)(Tb + base + 4) = p1;
      }
    }
    __syncthreads();
    for (int it = 0; it < 8; ++it){
      int idx = it*256 + t;
      int ro = idx >> 4, ch = idx & 15;
      uint4 val = *(const uint4*)(Tb + ro*256 + ((ch ^ (ro & 7)) << 4));
      int c = bx*128 - 512 + ro;          // absolute channel
      int n = m0 + ch*8;                  // aligned 8-key chunk
      float f0 = bf2f((u16)(val.x & 0xffff)), f1 = bf2f((u16)(val.x >> 16));
      float f2 = bf2f((u16)(val.y & 0xffff)), f3 = bf2f((u16)(val.y >> 16));
      float f4 = bf2f((u16)(val.z & 0xffff)), f5 = bf2f((u16)(val.z >> 16));
      float f6 = bf2f((u16)(val.w & 0xffff)), f7 = bf2f((u16)(val.w >> 16));
      int w0 = __builtin_amdgcn_cvt_pk_fp8_f32(f0, f1, 0, false);
      w0     = __builtin_amdgcn_cvt_pk_fp8_f32(f2, f3, w0, true);
      int w1 = __builtin_amdgcn_cvt_pk_fp8_f32(f4, f5, 0, false);
      w1     = __builtin_amdgcn_cvt_pk_fp8_f32(f6, f7, w1, true);
      size_t addr = ((size_t)b*128 + (n >> 5))*8192 +
                    (size_t)(c*32 + ((((n >> 3) & 3) ^ ((c >> 2) & 3)) << 3));
      uint2 wv; wv.x = (unsigned)w0; wv.y = (unsigned)w1;
      *(uint2*)(v + addr) = wv;
    }
  }
}

// ---------------- flash attention: S via MX-scaled 32x32x64 f8f6f4, PV via 32x32x16 fp8 ----------------
// waitcnt imms: vmcnt(4)=0x0F74, vmcnt(0)=0x0F70, lgkmcnt(0)=0xC07F
__global__ __launch_bounds__(256, 2) void flash_k(const u8* __restrict__ q, const u8* __restrict__ kt,
                                                  const u8* __restrict__ vt, u16* __restrict__ opart,
                                                  float* __restrict__ lpart){
  int n0 = blockIdx.x*128;
  int jh = blockIdx.y;
  int b  = blockIdx.z;
  __shared__ char buf[2][16384];   // 2 x 16KB: [K tile 8KB][V^T tile 8KB]
  int t = threadIdx.x, lane = t & 63, wave = t >> 6;
  int il = lane & 31;
  int h  = lane >> 5;

  // Q B-frags for scaled MFMA: lane holds Q[i=il][ch = si*64 + h*32 + e], e=0..31 (8 VGPRs x 4)
  i32x8 qf8[4];
  const u8* qrow = q + ((size_t)b*4096 + n0 + wave*32 + il)*256;
  #pragma unroll
  for (int si = 0; si < 4; ++si){
    uint4 a0 = *(const uint4*)(qrow + si*64 + h*32);
    uint4 a1 = *(const uint4*)(qrow + si*64 + h*32 + 16);
    qf8[si] = (i32x8){(int)a0.x,(int)a0.y,(int)a0.z,(int)a0.w,(int)a1.x,(int)a1.y,(int)a1.z,(int)a1.w};
  }

  f32x16 oacc[8];
  #pragma unroll
  for (int ct = 0; ct < 8; ++ct){
    #pragma unroll
    for (int r = 0; r < 16; ++r) oacc[ct][r] = 0.f;
  }
  float lsum = 0.f;

  size_t tb0 = ((size_t)b*128 + jh*32) * 8192;
  const char* gK = (const char*)kt + tb0;
  const char* gV = (const char*)vt + tb0;
  const char* gsrc = (wave < 2) ? (gK + wave*4096) : (gV + (wave - 2)*4096);
  unsigned lds_off = wave*4096;    // K in [0,8K), V in [8K,16K)

  // prime tiles 0 and 1
  {
    const char* g0 = gsrc + (size_t)lane*16;
    #pragma unroll
    for (int i = 0; i < 4; ++i)
      __builtin_amdgcn_global_load_lds((const __attribute__((address_space(1))) void*)(g0 + i*1024),
          (__attribute__((address_space(3))) void*)((char*)buf[0] + lds_off + i*1024), 16, 0, 0);
    const char* g1 = gsrc + 8192 + (size_t)lane*16;
    #pragma unroll
    for (int i = 0; i < 4; ++i)
      __builtin_amdgcn_global_load_lds((const __attribute__((address_space(1))) void*)(g1 + i*1024),
          (__attribute__((address_space(3))) void*)((char*)buf[1] + lds_off + i*1024), 16, 0, 0);
  }

  for (int jt = 0; jt < 32; ++jt){
    int p = jt & 1;
    asm volatile("" ::: "memory");
    if (jt < 31) __builtin_amdgcn_s_waitcnt(0x0F74);   // vmcnt(4)
    else         __builtin_amdgcn_s_waitcnt(0x0F70);   // vmcnt(0)
    __builtin_amdgcn_s_barrier();
    asm volatile("" ::: "memory");

    const char* klds = buf[p];
    const char* vlds = buf[p] + 8192;

    // S^T (32 keys x 32 queries) = K * Q^T: 4 MX-scaled K=64 MFMAs (scale = 1.0)
    f32x16 s0;
    #pragma unroll
    for (int r = 0; r < 16; ++r) s0[r] = 0.f;
    const char* krow = klds + il*256;
    #pragma unroll
    for (int si = 0; si < 4; ++si){
      uint2 c0 = *(const uint2*)(krow + (((si*8 + h*4 + 0) ^ (il & 15)) << 3));
      uint2 c1 = *(const uint2*)(krow + (((si*8 + h*4 + 1) ^ (il & 15)) << 3));
      uint2 c2 = *(const uint2*)(krow + (((si*8 + h*4 + 2) ^ (il & 15)) << 3));
      uint2 c3 = *(const uint2*)(krow + (((si*8 + h*4 + 3) ^ (il & 15)) << 3));
      i32x8 kf8 = (i32x8){(int)c0.x,(int)c0.y,(int)c1.x,(int)c1.y,(int)c2.x,(int)c2.y,(int)c3.x,(int)c3.y};
      s0 = __builtin_amdgcn_mfma_scale_f32_32x32x64_f8f6f4(kf8, qf8[si], s0,
                                                           0, 0, 0, SCL1, 0, SCL1);
    }
    // no-max softmax numerator; D: lane holds S^T[j=(r&3)+8(r>>2)+4h][i=il]
    float pv[16];
    #pragma unroll
    for (int r = 0; r < 16; ++r){
      float e = fast_exp2(s0[r] * QSCALE);
      pv[r] = e;
      lsum += e;
    }
    // C->A: pack to fp8, one shfl_xor(32) per K-step
    long pa[2];
    #pragma unroll
    for (int s2 = 0; s2 < 2; ++s2){
      int q0 = __builtin_amdgcn_cvt_pk_fp8_f32(pv[8*s2+0], pv[8*s2+1], 0, false);
      q0     = __builtin_amdgcn_cvt_pk_fp8_f32(pv[8*s2+2], pv[8*s2+3], q0, true);
      int q1 = __builtin_amdgcn_cvt_pk_fp8_f32(pv[8*s2+4], pv[8*s2+5], 0, false);
      q1     = __builtin_amdgcn_cvt_pk_fp8_f32(pv[8*s2+6], pv[8*s2+7], q1, true);
      int e  = h ? q0 : q1;
      int rr = __shfl_xor(e, 32, 64);
      unsigned lo = (unsigned)(h ? rr : q0);
      unsigned hi = (unsigned)(h ? q1 : rr);
      pa[s2] = ((long)hi << 32) | (long)lo;
    }
    // O += P*V (unchanged 32x32x16 fp8 path)
    #pragma unroll
    for (int s2 = 0; s2 < 2; ++s2){
      #pragma unroll
      for (int ct = 0; ct < 8; ++ct){
        int c = ct*32 + il;
        long vf = *(const long*)(vlds + c*32 + (((2*s2 + h) ^ ((c >> 2) & 3)) << 3));
        oacc[ct] = __builtin_amdgcn_mfma_f32_32x32x16_fp8_fp8(pa[s2], vf, oacc[ct], 0, 0, 0);
      }
    }

    asm volatile("" ::: "memory");
    __builtin_amdgcn_s_waitcnt(0xC07F);     // lgkmcnt(0)
    __builtin_amdgcn_s_barrier();
    asm volatile("" ::: "memory");
    if (jt + 2 < 32){
      const char* gn2 = gsrc + (size_t)(jt + 2)*8192 + (size_t)lane*16;
      #pragma unroll
      for (int i = 0; i < 4; ++i)
        __builtin_amdgcn_global_load_lds((const __attribute__((address_space(1))) void*)(gn2 + i*1024),
            (__attribute__((address_space(3))) void*)((char*)buf[p] + lds_off + i*1024), 16, 0, 0);
    }
  }

  // epilogue
  float tot = lsum + __shfl_xor(lsum, 32, 64);
  if (h == 0) lpart[(size_t)(jh*4 + b)*4096 + n0 + wave*32 + il] = tot;
  u16* obase = opart + ((size_t)(jh*4 + b)*4096 + n0 + wave*32)*256;
  #pragma unroll
  for (int ct = 0; ct < 8; ++ct){
    #pragma unroll
    for (int r = 0; r < 16; ++r){
      int i = (r & 3) + 8*(r >> 2) + 4*h;
      obase[(size_t)i*256 + ct*32 + il] = f2bf(oacc[ct][r]);
    }
  }
}

// ---------------- proj GEMM, n-tile 32 (512 blocks), fused combine + bias + residual ----------------
__global__ __launch_bounds__(256) void proj_gemm_k(const u16* __restrict__ opart, const float* __restrict__ lpart,
        const u16* __restrict__ wp, const float* __restrict__ pb, const float* __restrict__ x,
        float* __restrict__ out){
  int n0 = blockIdx.x*32;
  int b  = blockIdx.y;
  __shared__ u16 As[256*LDA];    // proj_w chunk 256 x 32
  __shared__ u16 Bs[32*LDA];     // combined ao chunk 32 x 32
  __shared__ float linv[32];
  int t = threadIdx.x, lane = t & 63, wave = t >> 6;
  int c15 = lane & 15, g = lane >> 4;
  if (t < 32){
    size_t row = (size_t)b*4096 + n0 + t;
    linv[t] = 1.0f / (lpart[row] + lpart[16384 + row] + lpart[32768 + row] + lpart[49152 + row]);
  }
  f32x4 acc[4][2];
  for (int mt = 0; mt < 4; ++mt) for (int nt = 0; nt < 2; ++nt) acc[mt][nt] = (f32x4){0.f,0.f,0.f,0.f};
  __syncthreads();
  for (int kk = 0; kk < 8; ++kk){
    int k0 = kk*32;
    for (int it = 0; it < 4; ++it){
      int idx = it*256 + t;
      int row = idx >> 2, ch = idx & 3;
      *(uint4*)(As + row*LDA + ch*8) = *(const uint4*)(wp + (size_t)row*256 + k0 + ch*8);
    }
    if (t < 128){
      int row = t >> 2, ch = t & 3;     // 32 rows x 4 chunks
      const u16* bptr = opart + ((size_t)b*4096 + n0 + row)*256 + k0 + ch*8;
      uint4 o0 = *(const uint4*)(bptr);
      uint4 o1 = *(const uint4*)(bptr + 4194304ull);
      uint4 o2 = *(const uint4*)(bptr + 8388608ull);
      uint4 o3 = *(const uint4*)(bptr + 12582912ull);
      float inv = linv[row];
      const unsigned* u0 = (const unsigned*)&o0;
      const unsigned* u1 = (const unsigned*)&o1;
      const unsigned* u2 = (const unsigned*)&o2;
      const unsigned* u3 = (const unsigned*)&o3;
      uint4 w;
      unsigned* wpk = (unsigned*)&w;
      for (int i = 0; i < 4; ++i){
        float lo = (bf2f((u16)(u0[i] & 0xffff)) + bf2f((u16)(u1[i] & 0xffff)) +
                    bf2f((u16)(u2[i] & 0xffff)) + bf2f((u16)(u3[i] & 0xffff))) * inv;
        float hi = (bf2f((u16)(u0[i] >> 16))    + bf2f((u16)(u1[i] >> 16)) +
                    bf2f((u16)(u2[i] >> 16))    + bf2f((u16)(u3[i] >> 16)))    * inv;
        wpk[i] = (unsigned)f2bf(lo) | ((unsigned)f2bf(hi) << 16);
      }
      *(uint4*)(Bs + row*LDA + ch*8) = w;
    }
    __syncthreads();
    short8 af[4], bfr[2];
    for (int mt = 0; mt < 4; ++mt) af[mt]  = *(const short8*)(As + (wave*64 + mt*16 + c15)*LDA + g*8);
    for (int nt = 0; nt < 2; ++nt) bfr[nt] = *(const short8*)(Bs + (nt*16 + c15)*LDA + g*8);
    for (int mt = 0; mt < 4; ++mt)
      for (int nt = 0; nt < 2; ++nt)
        acc[mt][nt] = __builtin_amdgcn_mfma_f32_16x16x32_bf16(af[mt], bfr[nt], acc[mt][nt], 0, 0, 0);
    __syncthreads();
  }
  for (int mt = 0; mt < 4; ++mt){
    for (int r = 0; r < 4; ++r){
      int o = wave*64 + mt*16 + g*4 + r;
      float bias = pb[o];
      for (int nt = 0; nt < 2; ++nt){
        int n = n0 + nt*16 + c15;
        size_t off = ((size_t)b*256 + o)*4096 + n;
        out[off] = x[off] + bias + acc[mt][nt][r];
      }
    }
  }
}

extern "C" void kernel_launch(void* const* d_in, const int* in_sizes, int n_in,
                              void* d_out, int out_size, void* d_ws, size_t ws_size,
                              hipStream_t stream){
  (void)in_sizes; (void)n_in; (void)out_size; (void)ws_size;
  const float* x     = (const float*)d_in[0];
  const float* gw    = (const float*)d_in[1];
  const float* gb    = (const float*)d_in[2];
  const float* qkvw  = (const float*)d_in[3];
  const float* qkvb  = (const float*)d_in[4];
  const float* projw = (const float*)d_in[5];
  const float* projb = (const float*)d_in[6];
  float* out = (float*)d_out;
  char* ws = (char*)d_ws;

  u16*   xn    = (u16*)(ws + XN_OFF);     // overlays opart (dead until flash writes it)
  u16*   op    = (u16*)(ws + OP_OFF);
  u8*    qws   = (u8*)(ws + QW_OFF);
  u8*    kws   = (u8*)(ws + KW_OFF);
  u8*    vws   = (u8*)(ws + VW_OFF);
  float* lp    = (float*)(ws + LP_OFF);
  u16*   wqb   = (u16*)(ws + WQB_OFF);
  u16*   wpb   = (u16*)(ws + WPB_OFF);
  float* pstat = (float*)(ws + ST_OFF);

  gnw_k<<<dim3(8, 66), 256, 0, stream>>>(x, qkvw, projw, pstat, wqb, wpb);
  gn_apply_k<<<dim3(64, 4, 4), 256, 0, stream>>>(x, gw, gb, pstat, xn);
  qkv_gemm_k<<<dim3(6, 32, 4), 256, 0, stream>>>(xn, wqb, qkvb, qws, kws, vws);
  flash_k<<<dim3(32, 4, 4), 256, 0, stream>>>(qws, kws, vws, op, lp);
  proj_gemm_k<<<dim3(128, 4), 256, 0, stream>>>(op, lp, wpb, projb, x, out);
}